// Round 5
// baseline (249.077 us; speedup 1.0000x reference)
//
#include <hip/hip_runtime.h>
#include <math.h>

#define LL 2048
#define DD 128
#define NS 16                          // 2 sources * 8 batches
#define SLAB (LL * DD)                 // 262144 elements per (src,n)
#define SCALE 0.08838834764831845f     // 1/sqrt(128)
#define NT 16                          // 128-row tiles per slab
#define NPAIR 136                      // NT*(NT+1)/2 upper-triangle pairs

typedef __attribute__((ext_vector_type(8))) short short8v;   // 8 bf16 (4 VGPR)
typedef __attribute__((ext_vector_type(4))) float float4v;   // MFMA C/D

__device__ __forceinline__ unsigned int f2bf(float f) {   // RNE, low 16 bits
    unsigned int u = __float_as_uint(f);
    u += 0x7fffu + ((u >> 16) & 1u);
    return u >> 16;
}
__device__ __forceinline__ void pair_decode(int p, int& ib, int& jb) {
    int i = 0;
    while (p >= NT - i) { p -= NT - i; ++i; }
    ib = i; jb = i + p;
}

// ns-first XCD remap (R3 win: FETCH 90->8.3 MB). XCD k owns slabs ns=k,k+8
// (1 MB each Ph+Pl) -> entire working set L2-resident per XCD.
__device__ __forceinline__ void work_decode(int bx, int by, int& pair, int& ns) {
    const int lin = by * NPAIR + bx;
    const int xcd = lin & 7;
    const int wi  = lin >> 3;          // 0..271
    const int h   = (wi >= NPAIR) ? 1 : 0;
    ns   = xcd + 8 * h;
    pair = wi - NPAIR * h;
}

// async global->LDS, 16B per lane; LDS dest = wave-uniform base + lane*16
__device__ __forceinline__ void gl_lds16(const void* g, void* l) {
    __builtin_amdgcn_global_load_lds(
        (const __attribute__((address_space(1))) void*)g,
        (__attribute__((address_space(3))) void*)l, 16, 0, 0);
}

// Stage one 128x32 bf16 chunk into a 512x16B-slot panel. Slot s = row*4+c'
// holds row's chunk oc = c' ^ ((row>>1)&3) (XOR involution, applied again on
// read). Linear LDS dest (gl_lds requirement), swizzled SOURCE + swizzled
// READ -> conflict-free ds_read_b128 (verified R3/R4: SQ_LDS_BANK_CONFLICT=0).
// 2 gl_lds16 per thread per panel (= 6 vmem ops/thread per 3-panel stage).
__device__ __forceinline__ void stage_panel(
    const unsigned short* __restrict__ gT, unsigned short* lbuf, int tid)
{
#pragma unroll
    for (int it = 0; it < 2; ++it) {
        const int s   = tid + it * 256;
        const int sb  = (tid & ~63) + it * 256;   // wave-uniform base slot
        const int row = s >> 2;
        const int oc  = (s & 3) ^ ((row >> 1) & 3);
        gl_lds16(gT + (size_t)row * DD + oc * 8, lbuf + (size_t)sb * 8);
    }
}

// ---------------------------------------------------------------------------
// Kernel 1: P = x @ W^T + b (fp32), split to P_hi/P_lo bf16 in d_out.
// Block: 64 l-rows x 128 d. Grid: (32 l-tiles, 16 ns) = 512 blocks.
// ---------------------------------------------------------------------------
__global__ __launch_bounds__(256, 4) void proj_kernel(
    const float* __restrict__ xt, const float* __restrict__ xf,
    const float* __restrict__ W,  const float* __restrict__ bias,
    unsigned short* __restrict__ Ph, unsigned short* __restrict__ Pl)
{
    __shared__ float Alds[64 * 36];
    __shared__ float Blds[128 * 36];
    __shared__ float bs[128];
    const int ns = blockIdx.y;
    const int l0 = blockIdx.x * 64;
    const int src = ns >> 3, n = ns & 7;
    const float* x = (src ? xf : xt) + (size_t)n * LL * DD;
    const int tid = threadIdx.x;
    const int ty = tid >> 4, tx = tid & 15;

    if (tid < 128) bs[tid] = bias[tid];
    __syncthreads();

    float acc[4][8];
#pragma unroll
    for (int i = 0; i < 4; ++i)
#pragma unroll
        for (int j = 0; j < 8; ++j) acc[i][j] = bs[tx + 16 * j];

    for (int kc = 0; kc < 4; ++kc) {
        __syncthreads();
#pragma unroll
        for (int t = 0; t < 2; ++t) {            // x: 64 x 32 = 512 float4
            int idx = tid + t * 256;
            int r = idx >> 3, k4 = (idx & 7) << 2;
            *(float4*)&Alds[r * 36 + k4] =
                *(const float4*)&x[(size_t)(l0 + r) * DD + kc * 32 + k4];
        }
#pragma unroll
        for (int t = 0; t < 4; ++t) {            // W: 128 x 32 = 1024 float4
            int idx = tid + t * 256;
            int r = idx >> 3, k4 = (idx & 7) << 2;
            *(float4*)&Blds[r * 36 + k4] =
                *(const float4*)&W[(size_t)r * DD + kc * 32 + k4];
        }
        __syncthreads();
#pragma unroll
        for (int k4 = 0; k4 < 32; k4 += 4) {
            float4 a4[4], b4[8];
#pragma unroll
            for (int i = 0; i < 4; ++i) a4[i] = *(const float4*)&Alds[(ty + 16 * i) * 36 + k4];
#pragma unroll
            for (int j = 0; j < 8; ++j) b4[j] = *(const float4*)&Blds[(tx + 16 * j) * 36 + k4];
#pragma unroll
            for (int i = 0; i < 4; ++i)
#pragma unroll
                for (int j = 0; j < 8; ++j) {
                    acc[i][j] = fmaf(a4[i].x, b4[j].x, acc[i][j]);
                    acc[i][j] = fmaf(a4[i].y, b4[j].y, acc[i][j]);
                    acc[i][j] = fmaf(a4[i].z, b4[j].z, acc[i][j]);
                    acc[i][j] = fmaf(a4[i].w, b4[j].w, acc[i][j]);
                }
        }
    }
#pragma unroll
    for (int i = 0; i < 4; ++i) {
        const size_t rowo = (size_t)ns * SLAB + (size_t)(l0 + ty + 16 * i) * DD;
#pragma unroll
        for (int j = 0; j < 8; ++j) {
            float p = acc[i][j];
            unsigned int hb = f2bf(p);
            float hf = __uint_as_float(hb << 16);
            unsigned int lb = f2bf(p - hf);
            Ph[rowo + tx + 16 * j] = (unsigned short)hb;
            Pl[rowo + tx + 16 * j] = (unsigned short)lb;
        }
    }
}

// ---------------------------------------------------------------------------
// MFMA bf16x3 GEMM core v6 (hi*hi + hi*lo + lo*hi).
// 4 waves in 2x2 grid; wave owns a 64x64 quadrant of S(ib,jb).
// COUNTED-VMCNT PIPELINE (T3+T4; R0-R4 lesson: drain-to-0 barriers cap all
// variants at ~53 us regardless of occupancy/memory):
//   - 3 rotating buffer sets x {Ah,Bh,Bl} panels (72 KB), distance-2
//     prefetch: phase kc stages kc+2.
//   - raw s_barrier + manual `s_waitcnt vmcnt(6)` pre-barrier: only DMA
//     issued TWO phases ago must land (long complete) -> near-zero wait;
//     this phase's 6 DMA stay in flight across the barrier.
//     FIFO correctness: next-phase panels are always >=6 ops older than the
//     newest 6, under any compiler interleave of pure loads.
//   - A-lo fully preloaded to registers in prologue (64 VGPR, cap 256 at
//     2 blocks/CU) -> zero compiler vmem loads inside the loop.
// Numerics identical to R0-R4: same products, same accumulation order.
// acc frag (16x16x32): out row = quad*4 + reg, out col = l16.
// ---------------------------------------------------------------------------
__device__ __forceinline__ void mfma_core(
    const unsigned short* __restrict__ Ph, const unsigned short* __restrict__ Pl,
    int ns, int ib, int jb, int tid,
    unsigned short (*pan)[4096],          // [ (kc%3)*3 + {Ah,Bh,Bl} ]
    float4v (&acc)[4][4])
{
    const int lane = tid & 63;
    const int quad = lane >> 4, l16 = lane & 15;
    const int wave = tid >> 6;
    const int wr = wave >> 1, wc = wave & 1;

    const unsigned short* sAh = Ph + (size_t)ns * SLAB + (size_t)ib * 128 * DD;
    const unsigned short* sAl = Pl + (size_t)ns * SLAB + (size_t)ib * 128 * DD;
    const unsigned short* sBh = Ph + (size_t)ns * SLAB + (size_t)jb * 128 * DD;
    const unsigned short* sBl = Pl + (size_t)ns * SLAB + (size_t)jb * 128 * DD;

#pragma unroll
    for (int i = 0; i < 4; ++i)
#pragma unroll
        for (int j = 0; j < 4; ++j)
#pragma unroll
            for (int r = 0; r < 4; ++r) acc[i][j][r] = 0.f;

    // ---- prologue: stage kc=0 -> buf0, kc=1 -> buf1 (12 DMA/thread) ----
    stage_panel(sAh,      pan[0], tid);
    stage_panel(sBh,      pan[1], tid);
    stage_panel(sBl,      pan[2], tid);
    stage_panel(sAh + 32, pan[3], tid);
    stage_panel(sBh + 32, pan[4], tid);
    stage_panel(sBl + 32, pan[5], tid);
    __builtin_amdgcn_sched_barrier(0);
    asm volatile("s_waitcnt vmcnt(6)" ::: "memory");   // kc0 resident; kc1 flying
    __builtin_amdgcn_sched_barrier(0);

    // A-lo preload: all 16 fragments (this wave's 64 rows x 4 k-chunks).
    // Issued after the vmcnt wait so they overlap phase 0; compiler inserts
    // its own (counted) waits before first use.
    short8v alf[4][4];
#pragma unroll
    for (int kc = 0; kc < 4; ++kc)
#pragma unroll
        for (int rt = 0; rt < 4; ++rt)
            alf[kc][rt] = *(const short8v*)
                &sAl[(size_t)(wr * 64 + rt * 16 + l16) * DD + kc * 32 + quad * 8];

    __builtin_amdgcn_s_barrier();          // all waves: kc0 panels complete

#pragma unroll
    for (int kc = 0; kc < 4; ++kc) {
        if (kc < 2) {                      // stage kc+2 into buf (kc+2)%3
            stage_panel(sAh + (kc + 2) * 32, pan[((kc + 2) % 3) * 3 + 0], tid);
            stage_panel(sBh + (kc + 2) * 32, pan[((kc + 2) % 3) * 3 + 1], tid);
            stage_panel(sBl + (kc + 2) * 32, pan[((kc + 2) % 3) * 3 + 2], tid);
        }
        const unsigned short* AhP = pan[(kc % 3) * 3 + 0];
        const unsigned short* BhP = pan[(kc % 3) * 3 + 1];
        const unsigned short* BlP = pan[(kc % 3) * 3 + 2];

        short8v ah[4], bh[4], bl[4];
#pragma unroll
        for (int rt = 0; rt < 4; ++rt) {
            const int r = wr * 64 + rt * 16 + l16;
            const int off = r * 32 + ((quad ^ ((r >> 1) & 3)) << 3);
            ah[rt] = *(const short8v*)&AhP[off];
        }
#pragma unroll
        for (int ct = 0; ct < 4; ++ct) {
            const int r = wc * 64 + ct * 16 + l16;
            const int off = r * 32 + ((quad ^ ((r >> 1) & 3)) << 3);
            bh[ct] = *(const short8v*)&BhP[off];
            bl[ct] = *(const short8v*)&BlP[off];
        }
        __builtin_amdgcn_s_setprio(1);
#pragma unroll
        for (int rt = 0; rt < 4; ++rt)
#pragma unroll
            for (int ct = 0; ct < 4; ++ct) {
                acc[rt][ct] = __builtin_amdgcn_mfma_f32_16x16x32_bf16(ah[rt], bh[ct], acc[rt][ct], 0, 0, 0);
                acc[rt][ct] = __builtin_amdgcn_mfma_f32_16x16x32_bf16(ah[rt], bl[ct], acc[rt][ct], 0, 0, 0);
                acc[rt][ct] = __builtin_amdgcn_mfma_f32_16x16x32_bf16(alf[kc][rt], bh[ct], acc[rt][ct], 0, 0, 0);
            }
        __builtin_amdgcn_s_setprio(0);
        __builtin_amdgcn_sched_barrier(0);
        // counted pre-barrier wait: ensure next phase's panels (staged >=1
        // phase ago) are resident; keep this phase's 6 DMA in flight.
        if (kc < 2)       { asm volatile("s_waitcnt vmcnt(6)" ::: "memory"); }
        else if (kc == 2) { asm volatile("s_waitcnt vmcnt(0)" ::: "memory"); }
        if (kc < 3) __builtin_amdgcn_s_barrier();
    }
}

// ---------------------------------------------------------------------------
// Kernel 2: per tile-pair UNSHIFTED softmax denominators: Zpart row sums of
// exp(s) for rows of BOTH blocks. Zpart: [(ns*16 + othertile)*2048 + row]
// ---------------------------------------------------------------------------
__global__ __launch_bounds__(256, 2) void stats_kernel(
    const unsigned short* __restrict__ Ph, const unsigned short* __restrict__ Pl,
    float* __restrict__ Zpart)
{
    __shared__ unsigned short pan[9][4096];                 // 72 KB panels
    __shared__ float Zr[128][2], Zc[128][2];                // 2 KB
    int pair, ns;  work_decode(blockIdx.x, blockIdx.y, pair, ns);
    int ib, jb;    pair_decode(pair, ib, jb);
    const int tid = threadIdx.x;
    const int lane = tid & 63, quad = lane >> 4, l16 = lane & 15, wave = tid >> 6;
    const int wr = wave >> 1, wc = wave & 1;

    float4v acc[4][4];
    mfma_core(Ph, Pl, ns, ib, jb, tid, pan, acc);

    float cs[4] = {0.f, 0.f, 0.f, 0.f};
#pragma unroll
    for (int rt = 0; rt < 4; ++rt)
#pragma unroll
        for (int rg = 0; rg < 4; ++rg) {
            float e[4];
            float s = 0.f;
#pragma unroll
            for (int ct = 0; ct < 4; ++ct) {
                e[ct] = __expf(acc[rt][ct][rg] * SCALE);
                s += e[ct]; cs[ct] += e[ct];
            }
            s += __shfl_xor(s, 1);
            s += __shfl_xor(s, 2);
            s += __shfl_xor(s, 4);
            s += __shfl_xor(s, 8);
            if (l16 == 0) Zr[wr * 64 + rt * 16 + quad * 4 + rg][wc] = s;
        }

    // transpose partials: sums over this wave's 64 rows for its 64 cols
#pragma unroll
    for (int ct = 0; ct < 4; ++ct) {
        float s = cs[ct];
        s += __shfl_xor(s, 16);
        s += __shfl_xor(s, 32);
        if (quad == 0) Zc[wc * 64 + ct * 16 + l16][wr] = s;
    }
    __syncthreads();
    if (tid < 128) {
        Zpart[(ns * 16 + jb) * LL + ib * 128 + tid] = Zr[tid][0] + Zr[tid][1];
        if (ib != jb)
            Zpart[(ns * 16 + ib) * LL + jb * 128 + tid] = Zc[tid][0] + Zc[tid][1];
    }
}

// ---------------------------------------------------------------------------
// Kernel 3: iZ[row] = 1 / sum of 16 per-tile partials
// ---------------------------------------------------------------------------
__global__ __launch_bounds__(256) void reduce_stats_kernel(
    const float* __restrict__ Zpart, float* __restrict__ iZfin)
{
    const int idx = blockIdx.x * 256 + threadIdx.x;   // ns*2048 + l
    const int ns = idx >> 11, l = idx & 2047;
    float Z = 0.f;
#pragma unroll
    for (int t = 0; t < 16; ++t) Z += Zpart[(ns * 16 + t) * LL + l];
    iZfin[idx] = 1.0f / Z;
}

// ---------------------------------------------------------------------------
// Kernel 4: recompute s (identical MFMA sequence), per-tile column partial
// sums of exp(s)*iZ_row for cols of BOTH blocks. Spart: [(ns*2048+m)*16+tile]
// ---------------------------------------------------------------------------
__global__ __launch_bounds__(256, 2) void colsum_kernel(
    const unsigned short* __restrict__ Ph, const unsigned short* __restrict__ Pl,
    const float* __restrict__ iZfin, float* __restrict__ Spart)
{
    __shared__ unsigned short pan[9][4096];                 // 72 KB panels
    __shared__ float Sr[128][2], Sc[128][2];                // 2 KB
    int pair, ns;  work_decode(blockIdx.x, blockIdx.y, pair, ns);
    int ib, jb;    pair_decode(pair, ib, jb);
    const int tid = threadIdx.x;
    const int lane = tid & 63, quad = lane >> 4, l16 = lane & 15, wave = tid >> 6;
    const int wr = wave >> 1, wc = wave & 1;

    float4v acc[4][4];
    mfma_core(Ph, Pl, ns, ib, jb, tid, pan, acc);

    float wrow[4][4];
#pragma unroll
    for (int rt = 0; rt < 4; ++rt)
#pragma unroll
        for (int rg = 0; rg < 4; ++rg)
            wrow[rt][rg] = iZfin[ns * LL + ib * 128 + wr * 64 + rt * 16 + quad * 4 + rg];
    float wcol[4];
#pragma unroll
    for (int ct = 0; ct < 4; ++ct)
        wcol[ct] = iZfin[ns * LL + jb * 128 + wc * 64 + ct * 16 + l16];

    float dsum[4] = {0.f, 0.f, 0.f, 0.f};
#pragma unroll
    for (int rt = 0; rt < 4; ++rt)
#pragma unroll
        for (int rg = 0; rg < 4; ++rg) {
            const int rl = wr * 64 + rt * 16 + quad * 4 + rg;
            float ts = 0.f;
#pragma unroll
            for (int ct = 0; ct < 4; ++ct) {
                float e = __expf(acc[rt][ct][rg] * SCALE);
                bool diag = (ib == jb) && (rl == wc * 64 + ct * 16 + l16);
                dsum[ct] += diag ? 0.f : e * wrow[rt][rg];
                ts += e * wcol[ct];
            }
            if (ib != jb) {
                ts += __shfl_xor(ts, 1);
                ts += __shfl_xor(ts, 2);
                ts += __shfl_xor(ts, 4);
                ts += __shfl_xor(ts, 8);
                if (l16 == 0) Sr[rl][wc] = ts;
            }
        }

#pragma unroll
    for (int ct = 0; ct < 4; ++ct) {
        float s = dsum[ct];
        s += __shfl_xor(s, 16);
        s += __shfl_xor(s, 32);
        if (quad == 0) Sc[wc * 64 + ct * 16 + l16][wr] = s;
    }
    __syncthreads();
    if (tid < 128) {
        Spart[((size_t)ns * LL + jb * 128 + tid) * 16 + ib] = Sc[tid][0] + Sc[tid][1];
        if (ib != jb)
            Spart[((size_t)ns * LL + ib * 128 + tid) * 16 + jb] = Sr[tid][0] + Sr[tid][1];
    }
}

// ---------------------------------------------------------------------------
// Kernel 5: score = fp64 sum of 16 tile partials; exact bottom-k mask via
// rank counting: mask[i] = #{j: score_j < score_i} < 1024
// ---------------------------------------------------------------------------
__global__ __launch_bounds__(1024) void mask_kernel(
    const float* __restrict__ Spart, unsigned char* __restrict__ maskbuf)
{
    __shared__ double s[LL];
    const int ns = blockIdx.x;
    const int half = blockIdx.y;
    const int tid = threadIdx.x;
#pragma unroll
    for (int h = 0; h < 2; ++h) {
        int m = tid + h * 1024;
        const float* sp = Spart + ((size_t)ns * LL + m) * 16;
        double a = 0.0;
#pragma unroll
        for (int t = 0; t < 16; ++t) a += (double)sp[t];
        s[m] = a;
    }
    __syncthreads();
    const int i = half * 1024 + tid;
    const double si = s[i];
    int cnt = 0;
    for (int j = 0; j < LL; ++j) cnt += (s[j] < si) ? 1 : 0;
    maskbuf[ns * LL + i] = (cnt < 1024) ? 1 : 0;
}

// ---------------------------------------------------------------------------
// Kernel 6: blend, all fp32.
// ---------------------------------------------------------------------------
__global__ __launch_bounds__(256) void blend_kernel(
    const float* __restrict__ xt, const float* __restrict__ xf,
    const unsigned char* __restrict__ maskbuf, float* __restrict__ out)
{
    const int idx4 = blockIdx.x * 256 + threadIdx.x;
    const size_t q = (size_t)idx4 * 4;
    const int row = (int)(q >> 7);
    const float4 a = *(const float4*)(xt + q);
    const float4 b = *(const float4*)(xf + q);
    const int mt = maskbuf[row] & 1;
    const int mf = maskbuf[16384 + row] & 1;
    const bool ct = mt && !mf;
    const bool cf = mf && !mt;
    float4 av;
    av.x = 0.5f * (a.x + b.x);  av.y = 0.5f * (a.y + b.y);
    av.z = 0.5f * (a.z + b.z);  av.w = 0.5f * (a.w + b.w);
    float4 o0 = ct ? av : a;
    float4 o1 = cf ? av : b;
    *(float4*)(out + q)                   = o0;
    *(float4*)(out + (size_t)2097152 + q) = o1;
}

// ---------------------------------------------------------------------------
extern "C" void kernel_launch(void* const* d_in, const int* in_sizes, int n_in,
                              void* d_out, int out_size, void* d_ws, size_t ws_size,
                              hipStream_t stream)
{
    const float* xt = (const float*)d_in[0];
    const float* xf = (const float*)d_in[1];
    const float* W  = (const float*)d_in[2];
    const float* b  = (const float*)d_in[3];
    float* out = (float*)d_out;

    // d_out (16.8 MB) holds P split: Ph bf16 [0,8.39MB), Pl bf16 [8.39,16.8MB).
    // Both dead before blend overwrites d_out.
    unsigned short* Ph = (unsigned short*)d_out;
    unsigned short* Pl = Ph + (size_t)NS * SLAB;

    float* Zpart = (float*)d_ws;                       // 16*16*2048 = 524288 f
    float* iZfin = Zpart + 16 * 16 * LL;               // 32768 f
    float* Spart = iZfin + NS * LL;                    // 524288 f
    unsigned char* maskbuf = (unsigned char*)(Spart + (size_t)16 * LL * 16);
    // total ws ~4.4 MB

    proj_kernel<<<dim3(32, NS), 256, 0, stream>>>(xt, xf, W, b, Ph, Pl);
    stats_kernel<<<dim3(NPAIR, NS), 256, 0, stream>>>(Ph, Pl, Zpart);
    reduce_stats_kernel<<<128, 256, 0, stream>>>(Zpart, iZfin);
    colsum_kernel<<<dim3(NPAIR, NS), 256, 0, stream>>>(Ph, Pl, iZfin, Spart);
    mask_kernel<<<dim3(NS, 2), 1024, 0, stream>>>(Spart, maskbuf);
    blend_kernel<<<2048, 256, 0, stream>>>(xt, xf, maskbuf, out);
}

// Round 6
// 243.601 us; speedup vs baseline: 1.0225x; 1.0225x over previous
//
#include <hip/hip_runtime.h>
#include <math.h>

#define LL 2048
#define DD 128
#define NS 16                          // 2 sources * 8 batches
#define SLAB (LL * DD)                 // 262144 elements per (src,n)
#define SCALE 0.08838834764831845f     // 1/sqrt(128)
#define NT 16                          // 128-row tiles per slab

typedef __attribute__((ext_vector_type(8))) short short8v;   // 8 bf16 (4 VGPR)
typedef __attribute__((ext_vector_type(4))) float float4v;   // MFMA C/D

__device__ __forceinline__ unsigned int f2bf(float f) {   // RNE, low 16 bits
    unsigned int u = __float_as_uint(f);
    u += 0x7fffu + ((u >> 16) & 1u);
    return u >> 16;
}

// strip decode: 256 blocks, 1/CU. XCD k owns slabs ns=k,k+8 (L2-resident).
__device__ __forceinline__ void strip_decode(int bx, int by, int& ib, int& ns) {
    const int lin = by * 16 + bx;
    const int xcd = lin & 7;
    const int w   = lin >> 3;          // 0..31
    ns = xcd + 8 * (w & 1);
    ib = w >> 1;
}

// async global->LDS, 16B per lane; LDS dest = wave-uniform base + lane*16
__device__ __forceinline__ void gl_lds16(const void* g, void* l) {
    __builtin_amdgcn_global_load_lds(
        (const __attribute__((address_space(1))) void*)g,
        (__attribute__((address_space(3))) void*)l, 16, 0, 0);
}

// Stage one 128x32 bf16 chunk into a 512x16B-slot panel (512-thread block:
// 1 DMA instr/wave). Slot s=row*4+c' holds row's chunk oc=c'^((row>>1)&3)
// (XOR involution; same perm on read). Conflict-free (verified R3-R5: 0).
__device__ __forceinline__ void stage512(
    const unsigned short* __restrict__ gT, unsigned short* lbuf, int tid)
{
    const int row = tid >> 2;
    const int oc  = (tid & 3) ^ ((row >> 1) & 3);
    const int sb  = tid & ~63;                    // wave-uniform base slot
    gl_lds16(gT + (size_t)row * DD + oc * 8, lbuf + (size_t)sb * 8);
}

// counted pre-barrier sync: only loads >=2 stage-pairs old must land
#define PSYNC(N) do { __builtin_amdgcn_sched_barrier(0); \
    asm volatile("s_waitcnt vmcnt(" #N ")" ::: "memory"); \
    __builtin_amdgcn_s_barrier(); \
    __builtin_amdgcn_sched_barrier(0); } while (0)

// one K-chunk: optional stage of phase+2, 4 ds_read_b128, 24 MFMA
#define KCSTEP(kc, SH, SL, DO_STAGE)                                          \
  { if (DO_STAGE) {                                                           \
        stage512((SH), pan[2 * (((kc) + 2) & 3)],     tid);                   \
        stage512((SL), pan[2 * (((kc) + 2) & 3) + 1], tid);                   \
    }                                                                         \
    const unsigned short* BhP = pan[2 * (kc)];                                \
    const unsigned short* BlP = pan[2 * (kc) + 1];                            \
    short8v bh[2], bl[2];                                                     \
    _Pragma("unroll")                                                         \
    for (int ct = 0; ct < 2; ++ct) {                                          \
        const int r = wc * 32 + ct * 16 + l16;                                \
        const int off = r * 32 + ((quad ^ ((r >> 1) & 3)) << 3);              \
        bh[ct] = *(const short8v*)&BhP[off];                                  \
        bl[ct] = *(const short8v*)&BlP[off];                                  \
    }                                                                         \
    __builtin_amdgcn_s_setprio(1);                                            \
    _Pragma("unroll")                                                         \
    for (int rt = 0; rt < 4; ++rt)                                            \
    _Pragma("unroll")                                                         \
    for (int ct = 0; ct < 2; ++ct) {                                          \
        acc[rt][ct] = __builtin_amdgcn_mfma_f32_16x16x32_bf16(ah[kc][rt], bh[ct], acc[rt][ct], 0, 0, 0); \
        acc[rt][ct] = __builtin_amdgcn_mfma_f32_16x16x32_bf16(ah[kc][rt], bl[ct], acc[rt][ct], 0, 0, 0); \
        acc[rt][ct] = __builtin_amdgcn_mfma_f32_16x16x32_bf16(al[kc][rt], bh[ct], acc[rt][ct], 0, 0, 0); \
    }                                                                         \
    __builtin_amdgcn_s_setprio(0); }

// ---------------------------------------------------------------------------
// Kernel 1: P = x @ W^T + b (fp32), split to P_hi/P_lo bf16 in d_out.
// ---------------------------------------------------------------------------
__global__ __launch_bounds__(256, 4) void proj_kernel(
    const float* __restrict__ xt, const float* __restrict__ xf,
    const float* __restrict__ W,  const float* __restrict__ bias,
    unsigned short* __restrict__ Ph, unsigned short* __restrict__ Pl)
{
    __shared__ float Alds[64 * 36];
    __shared__ float Blds[128 * 36];
    __shared__ float bs[128];
    const int ns = blockIdx.y;
    const int l0 = blockIdx.x * 64;
    const int src = ns >> 3, n = ns & 7;
    const float* x = (src ? xf : xt) + (size_t)n * LL * DD;
    const int tid = threadIdx.x;
    const int ty = tid >> 4, tx = tid & 15;

    if (tid < 128) bs[tid] = bias[tid];
    __syncthreads();

    float acc[4][8];
#pragma unroll
    for (int i = 0; i < 4; ++i)
#pragma unroll
        for (int j = 0; j < 8; ++j) acc[i][j] = bs[tx + 16 * j];

    for (int kc = 0; kc < 4; ++kc) {
        __syncthreads();
#pragma unroll
        for (int t = 0; t < 2; ++t) {
            int idx = tid + t * 256;
            int r = idx >> 3, k4 = (idx & 7) << 2;
            *(float4*)&Alds[r * 36 + k4] =
                *(const float4*)&x[(size_t)(l0 + r) * DD + kc * 32 + k4];
        }
#pragma unroll
        for (int t = 0; t < 4; ++t) {
            int idx = tid + t * 256;
            int r = idx >> 3, k4 = (idx & 7) << 2;
            *(float4*)&Blds[r * 36 + k4] =
                *(const float4*)&W[(size_t)r * DD + kc * 32 + k4];
        }
        __syncthreads();
#pragma unroll
        for (int k4 = 0; k4 < 32; k4 += 4) {
            float4 a4[4], b4[8];
#pragma unroll
            for (int i = 0; i < 4; ++i) a4[i] = *(const float4*)&Alds[(ty + 16 * i) * 36 + k4];
#pragma unroll
            for (int j = 0; j < 8; ++j) b4[j] = *(const float4*)&Blds[(tx + 16 * j) * 36 + k4];
#pragma unroll
            for (int i = 0; i < 4; ++i)
#pragma unroll
                for (int j = 0; j < 8; ++j) {
                    acc[i][j] = fmaf(a4[i].x, b4[j].x, acc[i][j]);
                    acc[i][j] = fmaf(a4[i].y, b4[j].y, acc[i][j]);
                    acc[i][j] = fmaf(a4[i].z, b4[j].z, acc[i][j]);
                    acc[i][j] = fmaf(a4[i].w, b4[j].w, acc[i][j]);
                }
        }
    }
#pragma unroll
    for (int i = 0; i < 4; ++i) {
        const size_t rowo = (size_t)ns * SLAB + (size_t)(l0 + ty + 16 * i) * DD;
#pragma unroll
        for (int j = 0; j < 8; ++j) {
            float p = acc[i][j];
            unsigned int hb = f2bf(p);
            float hf = __uint_as_float(hb << 16);
            unsigned int lb = f2bf(p - hf);
            Ph[rowo + tx + 16 * j] = (unsigned short)hb;
            Pl[rowo + tx + 16 * j] = (unsigned short)lb;
        }
    }
}

// ---------------------------------------------------------------------------
// Kernel 2 (strip): block (ib,ns) computes S(ib, all jb), accumulates FULL
// row sums Z of exp(s) in registers, writes iZ = 1/Z directly.
// 8 waves 2x4: wave owns rows wr*64..+64, cols wc*32..+32 of each tile.
// A hi+lo in registers (loaded once); B hi+lo LDS ring of 4 x 16KB,
// distance-2 counted vmcnt(2) -> 64-phase pipeline, no drain-to-0.
// ---------------------------------------------------------------------------
__global__ __launch_bounds__(512, 2) void stats_kernel(
    const unsigned short* __restrict__ Ph, const unsigned short* __restrict__ Pl,
    float* __restrict__ iZfin)
{
    __shared__ unsigned short pan[8][4096];                 // 64 KB B ring
    __shared__ float zl[128][4];
    int ib, ns;  strip_decode(blockIdx.x, blockIdx.y, ib, ns);
    const int tid = threadIdx.x;
    const int lane = tid & 63, quad = lane >> 4, l16 = lane & 15, wave = tid >> 6;
    const int wr = wave >> 2, wc = wave & 3;

    const unsigned short* sAh = Ph + (size_t)ns * SLAB + (size_t)ib * 128 * DD;
    const unsigned short* sAl = Pl + (size_t)ns * SLAB + (size_t)ib * 128 * DD;
    const unsigned short* sBh = Ph + (size_t)ns * SLAB;
    const unsigned short* sBl = Pl + (size_t)ns * SLAB;

    short8v ah[4][4], al[4][4];            // A frags: [kc][rt], 128 VGPR
#pragma unroll
    for (int kc = 0; kc < 4; ++kc)
#pragma unroll
        for (int rt = 0; rt < 4; ++rt) {
            const size_t o = (size_t)(wr * 64 + rt * 16 + l16) * DD + kc * 32 + quad * 8;
            ah[kc][rt] = *(const short8v*)&sAh[o];
            al[kc][rt] = *(const short8v*)&sAl[o];
        }
    stage512(sBh,      pan[0], tid);       // phase (0,0)
    stage512(sBl,      pan[1], tid);
    stage512(sBh + 32, pan[2], tid);       // phase (0,1)
    stage512(sBl + 32, pan[3], tid);
    PSYNC(2);                              // A + phase0 resident, phase1 flying

    float z[4][4];
#pragma unroll
    for (int rt = 0; rt < 4; ++rt)
#pragma unroll
        for (int rg = 0; rg < 4; ++rg) z[rt][rg] = 0.f;

    const unsigned short* bJh = sBh;
    const unsigned short* bJl = sBl;
#pragma unroll 1
    for (int jb = 0; jb < 16; ++jb) {
        float4v acc[4][2];
#pragma unroll
        for (int rt = 0; rt < 4; ++rt)
#pragma unroll
            for (int ct = 0; ct < 2; ++ct)
#pragma unroll
                for (int r = 0; r < 4; ++r) acc[rt][ct][r] = 0.f;

        const unsigned short* nJh = bJh + 128 * DD;
        const unsigned short* nJl = bJl + 128 * DD;
        const bool more = (jb < 15);

        KCSTEP(0, bJh + 64, bJl + 64, true);  PSYNC(2);
        KCSTEP(1, bJh + 96, bJl + 96, true);  PSYNC(2);
        KCSTEP(2, nJh,      nJl,      more);
        if (more) PSYNC(2); else PSYNC(0);
        KCSTEP(3, nJh + 32, nJl + 32, more);

        // per-jb: accumulate exp row sums (overlaps next staging latency)
#pragma unroll
        for (int rt = 0; rt < 4; ++rt)
#pragma unroll
            for (int rg = 0; rg < 4; ++rg) {
                float e0 = __expf(acc[rt][0][rg] * SCALE);
                float e1 = __expf(acc[rt][1][rg] * SCALE);
                z[rt][rg] += e0 + e1;
            }
        if (more) PSYNC(2);
        bJh = nJh;  bJl = nJl;
    }

    // epilogue: reduce over l16 (cols) then across wc waves via LDS
#pragma unroll
    for (int rt = 0; rt < 4; ++rt)
#pragma unroll
        for (int rg = 0; rg < 4; ++rg) {
            float s = z[rt][rg];
            s += __shfl_xor(s, 1);
            s += __shfl_xor(s, 2);
            s += __shfl_xor(s, 4);
            s += __shfl_xor(s, 8);
            z[rt][rg] = s;
        }
    if (l16 == 0) {
#pragma unroll
        for (int rt = 0; rt < 4; ++rt)
#pragma unroll
            for (int rg = 0; rg < 4; ++rg)
                zl[wr * 64 + rt * 16 + quad * 4 + rg][wc] = z[rt][rg];
    }
    __syncthreads();
    if (tid < 128) {
        float Z = zl[tid][0] + zl[tid][1] + zl[tid][2] + zl[tid][3];
        iZfin[ns * LL + ib * 128 + tid] = 1.0f / Z;
    }
}

// ---------------------------------------------------------------------------
// Kernel 3 (strip): recompute S strip, accumulate per-col partial sums of
// exp(s)*iZ_row (rows of ib) for ALL 2048 cols into LDS; one write phase.
// Spart: [(ns*2048+m)*16 + ib]  (16 partials per col, summed by mask_kernel)
// ---------------------------------------------------------------------------
__global__ __launch_bounds__(512, 2) void colsum_kernel(
    const unsigned short* __restrict__ Ph, const unsigned short* __restrict__ Pl,
    const float* __restrict__ iZfin, float* __restrict__ Spart)
{
    __shared__ unsigned short pan[8][4096];                 // 64 KB B ring
    __shared__ float scs[2048][2];                          // 16 KB col partials
    int ib, ns;  strip_decode(blockIdx.x, blockIdx.y, ib, ns);
    const int tid = threadIdx.x;
    const int lane = tid & 63, quad = lane >> 4, l16 = lane & 15, wave = tid >> 6;
    const int wr = wave >> 2, wc = wave & 3;

    const unsigned short* sAh = Ph + (size_t)ns * SLAB + (size_t)ib * 128 * DD;
    const unsigned short* sAl = Pl + (size_t)ns * SLAB + (size_t)ib * 128 * DD;
    const unsigned short* sBh = Ph + (size_t)ns * SLAB;
    const unsigned short* sBl = Pl + (size_t)ns * SLAB;

    float wrow[4][4];                      // iZ of own rows (fixed)
#pragma unroll
    for (int rt = 0; rt < 4; ++rt)
#pragma unroll
        for (int rg = 0; rg < 4; ++rg)
            wrow[rt][rg] = iZfin[ns * LL + ib * 128 + wr * 64 + rt * 16 + quad * 4 + rg];

    short8v ah[4][4], al[4][4];
#pragma unroll
    for (int kc = 0; kc < 4; ++kc)
#pragma unroll
        for (int rt = 0; rt < 4; ++rt) {
            const size_t o = (size_t)(wr * 64 + rt * 16 + l16) * DD + kc * 32 + quad * 8;
            ah[kc][rt] = *(const short8v*)&sAh[o];
            al[kc][rt] = *(const short8v*)&sAl[o];
        }
    stage512(sBh,      pan[0], tid);
    stage512(sBl,      pan[1], tid);
    stage512(sBh + 32, pan[2], tid);
    stage512(sBl + 32, pan[3], tid);
    PSYNC(2);

    const unsigned short* bJh = sBh;
    const unsigned short* bJl = sBl;
#pragma unroll 1
    for (int jb = 0; jb < 16; ++jb) {
        float4v acc[4][2];
#pragma unroll
        for (int rt = 0; rt < 4; ++rt)
#pragma unroll
            for (int ct = 0; ct < 2; ++ct)
#pragma unroll
                for (int r = 0; r < 4; ++r) acc[rt][ct][r] = 0.f;

        const unsigned short* nJh = bJh + 128 * DD;
        const unsigned short* nJl = bJl + 128 * DD;
        const bool more = (jb < 15);

        KCSTEP(0, bJh + 64, bJl + 64, true);  PSYNC(2);
        KCSTEP(1, bJh + 96, bJl + 96, true);  PSYNC(2);
        KCSTEP(2, nJh,      nJl,      more);
        if (more) PSYNC(2); else PSYNC(0);
        KCSTEP(3, nJh + 32, nJl + 32, more);

        // per-jb: weighted col partials (diag excluded when jb==ib)
        float colp0 = 0.f, colp1 = 0.f;
        const bool dgj = (jb == ib);
#pragma unroll
        for (int rt = 0; rt < 4; ++rt)
#pragma unroll
            for (int rg = 0; rg < 4; ++rg) {
                const int rl = wr * 64 + rt * 16 + quad * 4 + rg;
                float e0 = __expf(acc[rt][0][rg] * SCALE);
                float e1 = __expf(acc[rt][1][rg] * SCALE);
                bool s0 = dgj && (rl == wc * 32 + l16);
                bool s1 = dgj && (rl == wc * 32 + 16 + l16);
                colp0 += s0 ? 0.f : e0 * wrow[rt][rg];
                colp1 += s1 ? 0.f : e1 * wrow[rt][rg];
            }
        colp0 += __shfl_xor(colp0, 16);
        colp0 += __shfl_xor(colp0, 32);
        colp1 += __shfl_xor(colp1, 16);
        colp1 += __shfl_xor(colp1, 32);
        if (quad == 0) {
            scs[jb * 128 + wc * 32 + l16][wr]      = colp0;   // distinct slots
            scs[jb * 128 + wc * 32 + 16 + l16][wr] = colp1;   // per (jb,col,wr)
        }
        if (more) PSYNC(2);
        bJh = nJh;  bJl = nJl;
    }

    __syncthreads();
#pragma unroll
    for (int g = 0; g < 4; ++g) {
        const int m = tid + g * 512;
        Spart[((size_t)ns * LL + m) * 16 + ib] = scs[m][0] + scs[m][1];
    }
}

// ---------------------------------------------------------------------------
// Kernel 4: score = fp64 sum of 16 tile partials; exact bottom-k mask via
// rank counting: mask[i] = #{j: score_j < score_i} < 1024
// ---------------------------------------------------------------------------
__global__ __launch_bounds__(1024) void mask_kernel(
    const float* __restrict__ Spart, unsigned char* __restrict__ maskbuf)
{
    __shared__ double s[LL];
    const int ns = blockIdx.x;
    const int half = blockIdx.y;
    const int tid = threadIdx.x;
#pragma unroll
    for (int h = 0; h < 2; ++h) {
        int m = tid + h * 1024;
        const float* sp = Spart + ((size_t)ns * LL + m) * 16;
        double a = 0.0;
#pragma unroll
        for (int t = 0; t < 16; ++t) a += (double)sp[t];
        s[m] = a;
    }
    __syncthreads();
    const int i = half * 1024 + tid;
    const double si = s[i];
    int cnt = 0;
    for (int j = 0; j < LL; ++j) cnt += (s[j] < si) ? 1 : 0;
    maskbuf[ns * LL + i] = (cnt < 1024) ? 1 : 0;
}

// ---------------------------------------------------------------------------
// Kernel 5: blend, all fp32.
// ---------------------------------------------------------------------------
__global__ __launch_bounds__(256) void blend_kernel(
    const float* __restrict__ xt, const float* __restrict__ xf,
    const unsigned char* __restrict__ maskbuf, float* __restrict__ out)
{
    const int idx4 = blockIdx.x * 256 + threadIdx.x;
    const size_t q = (size_t)idx4 * 4;
    const int row = (int)(q >> 7);
    const float4 a = *(const float4*)(xt + q);
    const float4 b = *(const float4*)(xf + q);
    const int mt = maskbuf[row] & 1;
    const int mf = maskbuf[16384 + row] & 1;
    const bool ct = mt && !mf;
    const bool cf = mf && !mt;
    float4 av;
    av.x = 0.5f * (a.x + b.x);  av.y = 0.5f * (a.y + b.y);
    av.z = 0.5f * (a.z + b.z);  av.w = 0.5f * (a.w + b.w);
    float4 o0 = ct ? av : a;
    float4 o1 = cf ? av : b;
    *(float4*)(out + q)                   = o0;
    *(float4*)(out + (size_t)2097152 + q) = o1;
}

// ---------------------------------------------------------------------------
extern "C" void kernel_launch(void* const* d_in, const int* in_sizes, int n_in,
                              void* d_out, int out_size, void* d_ws, size_t ws_size,
                              hipStream_t stream)
{
    const float* xt = (const float*)d_in[0];
    const float* xf = (const float*)d_in[1];
    const float* W  = (const float*)d_in[2];
    const float* b  = (const float*)d_in[3];
    float* out = (float*)d_out;

    // d_out (16.8 MB) holds P split: Ph bf16 [0,8.39MB), Pl bf16 [8.39,16.8MB).
    unsigned short* Ph = (unsigned short*)d_out;
    unsigned short* Pl = Ph + (size_t)NS * SLAB;

    float* iZfin = (float*)d_ws;                       // 32768 f
    float* Spart = iZfin + NS * LL;                    // 524288 f
    unsigned char* maskbuf = (unsigned char*)(Spart + (size_t)16 * LL * 16);
    // total ws ~2.3 MB

    proj_kernel<<<dim3(32, NS), 256, 0, stream>>>(xt, xf, W, b, Ph, Pl);
    stats_kernel<<<dim3(16, 16), 512, 0, stream>>>(Ph, Pl, iZfin);
    colsum_kernel<<<dim3(16, 16), 512, 0, stream>>>(Ph, Pl, iZfin, Spart);
    mask_kernel<<<dim3(NS, 2), 1024, 0, stream>>>(Spart, maskbuf);
    blend_kernel<<<2048, 256, 0, stream>>>(xt, xf, maskbuf, out);
}

// Round 7
// 237.783 us; speedup vs baseline: 1.0475x; 1.0245x over previous
//
#include <hip/hip_runtime.h>
#include <math.h>

#define LL 2048
#define DD 128
#define NS 16                          // 2 sources * 8 batches
#define SLAB (LL * DD)                 // 262144 elements per (src,n)
#define SCALE 0.08838834764831845f     // 1/sqrt(128)

typedef __attribute__((ext_vector_type(8))) short short8v;   // 8 bf16 (4 VGPR)
typedef __attribute__((ext_vector_type(4))) float float4v;   // MFMA C/D

__device__ __forceinline__ unsigned int f2bf(float f) {   // RNE, low 16 bits
    unsigned int u = __float_as_uint(f);
    u += 0x7fffu + ((u >> 16) & 1u);
    return u >> 16;
}

// strip decode: 256 blocks, 1/CU. XCD k owns slabs ns=k,k+8 (L2-resident).
__device__ __forceinline__ void strip_decode(int bx, int by, int& ib, int& ns) {
    const int lin = by * 16 + bx;
    const int xcd = lin & 7;
    const int w   = lin >> 3;          // 0..31
    ns = xcd + 8 * (w & 1);
    ib = w >> 1;
}

// async global->LDS, 16B per lane; LDS dest = wave-uniform base + lane*16
__device__ __forceinline__ void gl_lds16(const void* g, void* l) {
    __builtin_amdgcn_global_load_lds(
        (const __attribute__((address_space(1))) void*)g,
        (__attribute__((address_space(3))) void*)l, 16, 0, 0);
}

// Stage one 128x32 bf16 chunk into a 512x16B-slot panel (512-thread block:
// 1 DMA instr/wave). Slot s=row*4+c' holds row's chunk oc=c'^((row>>1)&3)
// (XOR involution; same perm on read). Conflict-free (verified R3-R6: 0).
__device__ __forceinline__ void stage512(
    const unsigned short* __restrict__ gT, unsigned short* lbuf, int tid)
{
    const int row = tid >> 2;
    const int oc  = (tid & 3) ^ ((row >> 1) & 3);
    const int sb  = tid & ~63;                    // wave-uniform base slot
    gl_lds16(gT + (size_t)row * DD + oc * 8, lbuf + (size_t)sb * 8);
}

// stage one half-jb (2 kc) of B hi+lo into a 4-panel half-buffer (16 KB)
#define STAGE_HALF(DST, GH, GL, KC) do {                       \
    stage512((GH) + (KC) * 32,       (DST)[0], tid);           \
    stage512((GL) + (KC) * 32,       (DST)[1], tid);           \
    stage512((GH) + ((KC) + 1) * 32, (DST)[2], tid);           \
    stage512((GL) + ((KC) + 1) * 32, (DST)[3], tid); } while (0)

#define ZEROACC(ACC) do {                                      \
    _Pragma("unroll") for (int rt = 0; rt < 4; ++rt)           \
    _Pragma("unroll") for (int ct = 0; ct < 2; ++ct)           \
    _Pragma("unroll") for (int r = 0; r < 4; ++r) (ACC)[rt][ct][r] = 0.f; } while (0)

// one K-chunk: 4+4 ds_read_b128 (B from half-buffer CB, A-lo from Alpan),
// 24 MFMA (hh, hl, lh) using resident ah[AKC] regs.
#define KC2(ACC, CB, KI, AKC) do {                                            \
    const unsigned short* BhP = (CB)[2 * (KI)];                               \
    const unsigned short* BlP = (CB)[2 * (KI) + 1];                           \
    short8v bh[2], bl[2], alv[4];                                             \
    _Pragma("unroll")                                                         \
    for (int ct = 0; ct < 2; ++ct) {                                          \
        const int r = wc * 32 + ct * 16 + l16;                                \
        const int off = r * 32 + ((quad ^ ((r >> 1) & 3)) << 3);              \
        bh[ct] = *(const short8v*)&BhP[off];                                  \
        bl[ct] = *(const short8v*)&BlP[off];                                  \
    }                                                                         \
    _Pragma("unroll")                                                         \
    for (int rt = 0; rt < 4; ++rt) {                                          \
        const int r = wr * 64 + rt * 16 + l16;                                \
        const int off = r * 32 + ((quad ^ ((r >> 1) & 3)) << 3);              \
        alv[rt] = *(const short8v*)&Alpan[AKC][off];                          \
    }                                                                         \
    __builtin_amdgcn_s_setprio(1);                                            \
    _Pragma("unroll")                                                         \
    for (int rt = 0; rt < 4; ++rt)                                            \
    _Pragma("unroll")                                                         \
    for (int ct = 0; ct < 2; ++ct) {                                          \
        (ACC)[rt][ct] = __builtin_amdgcn_mfma_f32_16x16x32_bf16(ah[AKC][rt], bh[ct], (ACC)[rt][ct], 0, 0, 0); \
        (ACC)[rt][ct] = __builtin_amdgcn_mfma_f32_16x16x32_bf16(ah[AKC][rt], bl[ct], (ACC)[rt][ct], 0, 0, 0); \
        (ACC)[rt][ct] = __builtin_amdgcn_mfma_f32_16x16x32_bf16(alv[rt],     bh[ct], (ACC)[rt][ct], 0, 0, 0); \
    }                                                                         \
    __builtin_amdgcn_s_setprio(0); } while (0)

// sweep-1 deferred epilogue: row-sum exp accumulation (same order as R6)
#define EPI1(ACC) do {                                         \
    _Pragma("unroll") for (int rt = 0; rt < 4; ++rt)           \
    _Pragma("unroll") for (int rg = 0; rg < 4; ++rg) {         \
        float e0 = __expf((ACC)[rt][0][rg] * SCALE);           \
        float e1 = __expf((ACC)[rt][1][rg] * SCALE);           \
        z[rt][rg] += e0 + e1; } } while (0)

// sweep-2 deferred epilogue: weighted col partials (diag excluded), per R6
#define EPI2(ACC, JBV) do {                                    \
    float colp0 = 0.f, colp1 = 0.f;                            \
    const bool dgj = ((JBV) == ib);                            \
    _Pragma("unroll") for (int rt = 0; rt < 4; ++rt)           \
    _Pragma("unroll") for (int rg = 0; rg < 4; ++rg) {         \
        const int rl = wr * 64 + rt * 16 + quad * 4 + rg;      \
        float e0 = __expf((ACC)[rt][0][rg] * SCALE);           \
        float e1 = __expf((ACC)[rt][1][rg] * SCALE);           \
        bool s0 = dgj && (rl == wc * 32 + l16);                \
        bool s1 = dgj && (rl == wc * 32 + 16 + l16);           \
        colp0 += s0 ? 0.f : e0 * wrow[rt][rg];                 \
        colp1 += s1 ? 0.f : e1 * wrow[rt][rg]; }               \
    colp0 += __shfl_xor(colp0, 16); colp0 += __shfl_xor(colp0, 32); \
    colp1 += __shfl_xor(colp1, 16); colp1 += __shfl_xor(colp1, 32); \
    if (quad == 0) {                                           \
        scs[(JBV) * 128 + wc * 32 + l16][wr]      = colp0;     \
        scs[(JBV) * 128 + wc * 32 + 16 + l16][wr] = colp1; } } while (0)

// ---------------------------------------------------------------------------
// Kernel 1: P = x @ W^T + b (fp32), split to P_hi/P_lo bf16 in d_out.
// ---------------------------------------------------------------------------
__global__ __launch_bounds__(256, 4) void proj_kernel(
    const float* __restrict__ xt, const float* __restrict__ xf,
    const float* __restrict__ W,  const float* __restrict__ bias,
    unsigned short* __restrict__ Ph, unsigned short* __restrict__ Pl)
{
    __shared__ float Alds[64 * 36];
    __shared__ float Blds[128 * 36];
    __shared__ float bs[128];
    const int ns = blockIdx.y;
    const int l0 = blockIdx.x * 64;
    const int src = ns >> 3, n = ns & 7;
    const float* x = (src ? xf : xt) + (size_t)n * LL * DD;
    const int tid = threadIdx.x;
    const int ty = tid >> 4, tx = tid & 15;

    if (tid < 128) bs[tid] = bias[tid];
    __syncthreads();

    float acc[4][8];
#pragma unroll
    for (int i = 0; i < 4; ++i)
#pragma unroll
        for (int j = 0; j < 8; ++j) acc[i][j] = bs[tx + 16 * j];

    for (int kc = 0; kc < 4; ++kc) {
        __syncthreads();
#pragma unroll
        for (int t = 0; t < 2; ++t) {
            int idx = tid + t * 256;
            int r = idx >> 3, k4 = (idx & 7) << 2;
            *(float4*)&Alds[r * 36 + k4] =
                *(const float4*)&x[(size_t)(l0 + r) * DD + kc * 32 + k4];
        }
#pragma unroll
        for (int t = 0; t < 4; ++t) {
            int idx = tid + t * 256;
            int r = idx >> 3, k4 = (idx & 7) << 2;
            *(float4*)&Blds[r * 36 + k4] =
                *(const float4*)&W[(size_t)r * DD + kc * 32 + k4];
        }
        __syncthreads();
#pragma unroll
        for (int k4 = 0; k4 < 32; k4 += 4) {
            float4 a4[4], b4[8];
#pragma unroll
            for (int i = 0; i < 4; ++i) a4[i] = *(const float4*)&Alds[(ty + 16 * i) * 36 + k4];
#pragma unroll
            for (int j = 0; j < 8; ++j) b4[j] = *(const float4*)&Blds[(tx + 16 * j) * 36 + k4];
#pragma unroll
            for (int i = 0; i < 4; ++i)
#pragma unroll
                for (int j = 0; j < 8; ++j) {
                    acc[i][j] = fmaf(a4[i].x, b4[j].x, acc[i][j]);
                    acc[i][j] = fmaf(a4[i].y, b4[j].y, acc[i][j]);
                    acc[i][j] = fmaf(a4[i].z, b4[j].z, acc[i][j]);
                    acc[i][j] = fmaf(a4[i].w, b4[j].w, acc[i][j]);
                }
        }
    }
#pragma unroll
    for (int i = 0; i < 4; ++i) {
        const size_t rowo = (size_t)ns * SLAB + (size_t)(l0 + ty + 16 * i) * DD;
#pragma unroll
        for (int j = 0; j < 8; ++j) {
            float p = acc[i][j];
            unsigned int hb = f2bf(p);
            float hf = __uint_as_float(hb << 16);
            unsigned int lb = f2bf(p - hf);
            Ph[rowo + tx + 16 * j] = (unsigned short)hb;
            Pl[rowo + tx + 16 * j] = (unsigned short)lb;
        }
    }
}

// ---------------------------------------------------------------------------
// Kernel 2 (fused strip): block (ib,ns) makes TWO sweeps over S(ib, all jb).
// Sweep 1: row sums Z of exp(s) -> iZ in-register (no global roundtrip).
// Sweep 2: col partials of exp(s)*iZ_row -> Spart.
// A-hi in regs (64 VGPR, loaded once for both sweeps); A-lo in static LDS
// panels (32 KB, staged once); B hi+lo double-buffered half-jb (2 kc)
// phases, one __syncthreads per phase — each phase's DMA was issued a full
// phase (~1.9k cyc) earlier, so the drain is cheap (R0-R5 lesson: it's the
// ISSUE-TO-WAIT DISTANCE that matters, not the drain count).
// Deferred epilogue: accA/accB ping-pong; jb's exp/VALU runs inside jb+1's
// first MFMA phase (same scheduling region -> pipes overlap; R6 lesson:
// barrier-lockstep serialized 28% VALU with 33% MFMA).
// ---------------------------------------------------------------------------
__global__ __launch_bounds__(512, 2) void score_kernel(
    const unsigned short* __restrict__ Ph, const unsigned short* __restrict__ Pl,
    float* __restrict__ Spart)
{
    __shared__ unsigned short pan[2][4][4096];   // 64 KB B double-buffer
    __shared__ unsigned short Alpan[4][4096];    // 32 KB A-lo panels (static)
    __shared__ float scs[2048][2];               // 16 KB col partials
    __shared__ float zl[128][4];                 // 2 KB Z cross-wave
    int ib, ns;  strip_decode(blockIdx.x, blockIdx.y, ib, ns);
    const int tid = threadIdx.x;
    const int lane = tid & 63, quad = lane >> 4, l16 = lane & 15, wave = tid >> 6;
    const int wr = wave >> 2, wc = wave & 3;

    const unsigned short* sAh = Ph + (size_t)ns * SLAB + (size_t)ib * 128 * DD;
    const unsigned short* sAl = Pl + (size_t)ns * SLAB + (size_t)ib * 128 * DD;
    const unsigned short* sBh = Ph + (size_t)ns * SLAB;
    const unsigned short* sBl = Pl + (size_t)ns * SLAB;

    // ---- prologue: A-lo panels, A-hi regs, first half of jb0 ----
    stage512(sAl,      Alpan[0], tid);
    stage512(sAl + 32, Alpan[1], tid);
    stage512(sAl + 64, Alpan[2], tid);
    stage512(sAl + 96, Alpan[3], tid);
    STAGE_HALF(pan[0], sBh, sBl, 0);
    short8v ah[4][4];
#pragma unroll
    for (int kc = 0; kc < 4; ++kc)
#pragma unroll
        for (int rt = 0; rt < 4; ++rt)
            ah[kc][rt] = *(const short8v*)
                &sAh[(size_t)(wr * 64 + rt * 16 + l16) * DD + kc * 32 + quad * 8];
    __syncthreads();

    float4v accA[4][2], accB[4][2];
    float z[4][4];
#pragma unroll
    for (int rt = 0; rt < 4; ++rt)
#pragma unroll
        for (int rg = 0; rg < 4; ++rg) z[rt][rg] = 0.f;

    // ================= sweep 1: Z row sums =================
#pragma unroll 1
    for (int jp = 0; jp < 8; ++jp) {
        const unsigned short* b0h = sBh + (size_t)(2 * jp) * 128 * DD;
        const unsigned short* b0l = sBl + (size_t)(2 * jp) * 128 * DD;
        const unsigned short* b1h = b0h + 128 * DD;
        const unsigned short* b1l = b0l + 128 * DD;
        const unsigned short* b2h = b1h + 128 * DD;
        const unsigned short* b2l = b1l + 128 * DD;

        ZEROACC(accA);                         // phase A0: jb even, kc0-1
        STAGE_HALF(pan[1], b0h, b0l, 2);
        KC2(accA, pan[0], 0, 0);
        KC2(accA, pan[0], 1, 1);
        if (jp) EPI1(accB);                    // epilogue of jb 2jp-1
        __syncthreads();

        STAGE_HALF(pan[0], b1h, b1l, 0);       // phase A1: jb even, kc2-3
        KC2(accA, pan[1], 0, 2);
        KC2(accA, pan[1], 1, 3);
        __syncthreads();

        ZEROACC(accB);                         // phase B0: jb odd, kc0-1
        STAGE_HALF(pan[1], b1h, b1l, 2);
        KC2(accB, pan[0], 0, 0);
        KC2(accB, pan[0], 1, 1);
        EPI1(accA);                            // epilogue of jb 2jp
        __syncthreads();

        if (jp < 7) STAGE_HALF(pan[0], b2h, b2l, 0);   // phase B1: kc2-3
        KC2(accB, pan[1], 0, 2);
        KC2(accB, pan[1], 1, 3);
        __syncthreads();
    }
    EPI1(accB);                                // jb 15

    // ---- Z reduce -> per-thread iZ row weights (same fp32 ops as R6) ----
#pragma unroll
    for (int rt = 0; rt < 4; ++rt)
#pragma unroll
        for (int rg = 0; rg < 4; ++rg) {
            float s = z[rt][rg];
            s += __shfl_xor(s, 1);
            s += __shfl_xor(s, 2);
            s += __shfl_xor(s, 4);
            s += __shfl_xor(s, 8);
            if (l16 == 0) zl[wr * 64 + rt * 16 + quad * 4 + rg][wc] = s;
        }
    STAGE_HALF(pan[0], sBh, sBl, 0);           // prefetch sweep-2 jb0
    __syncthreads();
    float wrow[4][4];
#pragma unroll
    for (int rt = 0; rt < 4; ++rt)
#pragma unroll
        for (int rg = 0; rg < 4; ++rg) {
            const int row = wr * 64 + rt * 16 + quad * 4 + rg;
            wrow[rt][rg] = 1.0f / (zl[row][0] + zl[row][1] + zl[row][2] + zl[row][3]);
        }

    // ================= sweep 2: weighted col partials =================
#pragma unroll 1
    for (int jp = 0; jp < 8; ++jp) {
        const unsigned short* b0h = sBh + (size_t)(2 * jp) * 128 * DD;
        const unsigned short* b0l = sBl + (size_t)(2 * jp) * 128 * DD;
        const unsigned short* b1h = b0h + 128 * DD;
        const unsigned short* b1l = b0l + 128 * DD;
        const unsigned short* b2h = b1h + 128 * DD;
        const unsigned short* b2l = b1l + 128 * DD;

        ZEROACC(accA);
        STAGE_HALF(pan[1], b0h, b0l, 2);
        KC2(accA, pan[0], 0, 0);
        KC2(accA, pan[0], 1, 1);
        if (jp) EPI2(accB, 2 * jp - 1);
        __syncthreads();

        STAGE_HALF(pan[0], b1h, b1l, 0);
        KC2(accA, pan[1], 0, 2);
        KC2(accA, pan[1], 1, 3);
        __syncthreads();

        ZEROACC(accB);
        STAGE_HALF(pan[1], b1h, b1l, 2);
        KC2(accB, pan[0], 0, 0);
        KC2(accB, pan[0], 1, 1);
        EPI2(accA, 2 * jp);
        __syncthreads();

        if (jp < 7) STAGE_HALF(pan[0], b2h, b2l, 0);
        KC2(accB, pan[1], 0, 2);
        KC2(accB, pan[1], 1, 3);
        __syncthreads();
    }
    EPI2(accB, 15);

    __syncthreads();
#pragma unroll
    for (int g = 0; g < 4; ++g) {
        const int m = tid + g * 512;
        Spart[((size_t)ns * LL + m) * 16 + ib] = scs[m][0] + scs[m][1];
    }
}

// ---------------------------------------------------------------------------
// Kernel 3: score = fp64 sum of 16 tile partials; exact bottom-k mask via
// rank counting: mask[i] = #{j: score_j < score_i} < 1024
// ---------------------------------------------------------------------------
__global__ __launch_bounds__(1024) void mask_kernel(
    const float* __restrict__ Spart, unsigned char* __restrict__ maskbuf)
{
    __shared__ double s[LL];
    const int ns = blockIdx.x;
    const int half = blockIdx.y;
    const int tid = threadIdx.x;
#pragma unroll
    for (int h = 0; h < 2; ++h) {
        int m = tid + h * 1024;
        const float* sp = Spart + ((size_t)ns * LL + m) * 16;
        double a = 0.0;
#pragma unroll
        for (int t = 0; t < 16; ++t) a += (double)sp[t];
        s[m] = a;
    }
    __syncthreads();
    const int i = half * 1024 + tid;
    const double si = s[i];
    int cnt = 0;
    for (int j = 0; j < LL; ++j) cnt += (s[j] < si) ? 1 : 0;
    maskbuf[ns * LL + i] = (cnt < 1024) ? 1 : 0;
}

// ---------------------------------------------------------------------------
// Kernel 4: blend, all fp32.
// ---------------------------------------------------------------------------
__global__ __launch_bounds__(256) void blend_kernel(
    const float* __restrict__ xt, const float* __restrict__ xf,
    const unsigned char* __restrict__ maskbuf, float* __restrict__ out)
{
    const int idx4 = blockIdx.x * 256 + threadIdx.x;
    const size_t q = (size_t)idx4 * 4;
    const int row = (int)(q >> 7);
    const float4 a = *(const float4*)(xt + q);
    const float4 b = *(const float4*)(xf + q);
    const int mt = maskbuf[row] & 1;
    const int mf = maskbuf[16384 + row] & 1;
    const bool ct = mt && !mf;
    const bool cf = mf && !mt;
    float4 av;
    av.x = 0.5f * (a.x + b.x);  av.y = 0.5f * (a.y + b.y);
    av.z = 0.5f * (a.z + b.z);  av.w = 0.5f * (a.w + b.w);
    float4 o0 = ct ? av : a;
    float4 o1 = cf ? av : b;
    *(float4*)(out + q)                   = o0;
    *(float4*)(out + (size_t)2097152 + q) = o1;
}

// ---------------------------------------------------------------------------
extern "C" void kernel_launch(void* const* d_in, const int* in_sizes, int n_in,
                              void* d_out, int out_size, void* d_ws, size_t ws_size,
                              hipStream_t stream)
{
    const float* xt = (const float*)d_in[0];
    const float* xf = (const float*)d_in[1];
    const float* W  = (const float*)d_in[2];
    const float* b  = (const float*)d_in[3];
    float* out = (float*)d_out;

    // d_out (16.8 MB) holds P split: Ph bf16 [0,8.39MB), Pl bf16 [8.39,16.8MB).
    unsigned short* Ph = (unsigned short*)d_out;
    unsigned short* Pl = Ph + (size_t)NS * SLAB;

    float* Spart = (float*)d_ws;                       // 524288 f
    unsigned char* maskbuf = (unsigned char*)(Spart + (size_t)16 * LL * 16);
    // total ws ~2.2 MB

    proj_kernel<<<dim3(32, NS), 256, 0, stream>>>(xt, xf, W, b, Ph, Pl);
    score_kernel<<<dim3(16, 16), 512, 0, stream>>>(Ph, Pl, Spart);
    mask_kernel<<<dim3(NS, 2), 1024, 0, stream>>>(Spart, maskbuf);
    blend_kernel<<<2048, 256, 0, stream>>>(xt, xf, maskbuf, out);
}

// Round 8
// 220.069 us; speedup vs baseline: 1.1318x; 1.0805x over previous
//
#include <hip/hip_runtime.h>
#include <math.h>

#define LL 2048
#define DD 128
#define NS 16                          // 2 sources * 8 batches
#define SLAB (LL * DD)                 // 262144 elements per (src,n)
#define SCALE 0.08838834764831845f     // 1/sqrt(128)

typedef __attribute__((ext_vector_type(8))) short short8v;   // 8 bf16 (4 VGPR)
typedef __attribute__((ext_vector_type(4))) float float4v;   // MFMA C/D

__device__ __forceinline__ unsigned int f2bf(float f) {   // RNE, low 16 bits
    unsigned int u = __float_as_uint(f);
    u += 0x7fffu + ((u >> 16) & 1u);
    return u >> 16;
}

// strip decode: 256 blocks, 1/CU. XCD k owns slabs ns=k,k+8 (L2-resident).
__device__ __forceinline__ void strip_decode(int bx, int by, int& ib, int& ns) {
    const int lin = by * 16 + bx;
    const int xcd = lin & 7;
    const int w   = lin >> 3;          // 0..31
    ns = xcd + 8 * (w & 1);
    ib = w >> 1;
}

// async global->LDS, 16B per lane; LDS dest = wave-uniform base + lane*16
__device__ __forceinline__ void gl_lds16(const void* g, void* l) {
    __builtin_amdgcn_global_load_lds(
        (const __attribute__((address_space(1))) void*)g,
        (__attribute__((address_space(3))) void*)l, 16, 0, 0);
}

// Stage one 128x32 bf16 chunk into a 512x16B-slot panel (512-thread block:
// 1 DMA instr/wave). Slot s=row*4+c' holds row's chunk oc=c'^((row>>1)&3)
// (XOR involution; same perm on read). Conflict-free (verified R3-R7: 0).
__device__ __forceinline__ void stage512(
    const unsigned short* __restrict__ gT, unsigned short* lbuf, int tid)
{
    const int row = tid >> 2;
    const int oc  = (tid & 3) ^ ((row >> 1) & 3);
    const int sb  = tid & ~63;                    // wave-uniform base slot
    gl_lds16(gT + (size_t)row * DD + oc * 8, lbuf + (size_t)sb * 8);
}

// stage one half-jb (2 kc) of B hi+lo into a 4-panel half-buffer (16 KB)
#define STAGE_HALF(DST, GH, GL, KC) do {                       \
    stage512((GH) + (KC) * 32,       (DST)[0], tid);           \
    stage512((GL) + (KC) * 32,       (DST)[1], tid);           \
    stage512((GH) + ((KC) + 1) * 32, (DST)[2], tid);           \
    stage512((GL) + ((KC) + 1) * 32, (DST)[3], tid); } while (0)

#define ZEROACC(ACC) do {                                      \
    _Pragma("unroll") for (int rt = 0; rt < 4; ++rt)           \
    _Pragma("unroll") for (int ct = 0; ct < 2; ++ct)           \
    _Pragma("unroll") for (int r = 0; r < 4; ++r) (ACC)[rt][ct][r] = 0.f; } while (0)

// one K-chunk: 4+4 ds_read_b128 (B from half-buffer CB, A-lo from Alpan),
// 24 MFMA (hh, hl, lh) using resident ah[AKC] regs.
#define KC2(ACC, CB, KI, AKC) do {                                            \
    const unsigned short* BhP = (CB)[2 * (KI)];                               \
    const unsigned short* BlP = (CB)[2 * (KI) + 1];                           \
    short8v bh[2], bl[2], alv[4];                                             \
    _Pragma("unroll")                                                         \
    for (int ct = 0; ct < 2; ++ct) {                                          \
        const int r = wc * 32 + ct * 16 + l16;                                \
        const int off = r * 32 + ((quad ^ ((r >> 1) & 3)) << 3);              \
        bh[ct] = *(const short8v*)&BhP[off];                                  \
        bl[ct] = *(const short8v*)&BlP[off];                                  \
    }                                                                         \
    _Pragma("unroll")                                                         \
    for (int rt = 0; rt < 4; ++rt) {                                          \
        const int r = wr * 64 + rt * 16 + l16;                                \
        const int off = r * 32 + ((quad ^ ((r >> 1) & 3)) << 3);              \
        alv[rt] = *(const short8v*)&Alpan[AKC][off];                          \
    }                                                                         \
    __builtin_amdgcn_s_setprio(1);                                            \
    _Pragma("unroll")                                                         \
    for (int rt = 0; rt < 4; ++rt)                                            \
    _Pragma("unroll")                                                         \
    for (int ct = 0; ct < 2; ++ct) {                                          \
        (ACC)[rt][ct] = __builtin_amdgcn_mfma_f32_16x16x32_bf16(ah[AKC][rt], bh[ct], (ACC)[rt][ct], 0, 0, 0); \
        (ACC)[rt][ct] = __builtin_amdgcn_mfma_f32_16x16x32_bf16(ah[AKC][rt], bl[ct], (ACC)[rt][ct], 0, 0, 0); \
        (ACC)[rt][ct] = __builtin_amdgcn_mfma_f32_16x16x32_bf16(alv[rt],     bh[ct], (ACC)[rt][ct], 0, 0, 0); \
    }                                                                         \
    __builtin_amdgcn_s_setprio(0); } while (0)

// sweep-1 deferred epilogue: row-sum exp accumulation (same order as R6/R7)
#define EPI1(ACC) do {                                         \
    _Pragma("unroll") for (int rt = 0; rt < 4; ++rt)           \
    _Pragma("unroll") for (int rg = 0; rg < 4; ++rg) {         \
        float e0 = __expf((ACC)[rt][0][rg] * SCALE);           \
        float e1 = __expf((ACC)[rt][1][rg] * SCALE);           \
        z[rt][rg] += e0 + e1; } } while (0)

// sweep-2 deferred epilogue: weighted col partials (diag excluded), per R6/R7
#define EPI2(ACC, JBV) do {                                    \
    float colp0 = 0.f, colp1 = 0.f;                            \
    const bool dgj = ((JBV) == ib);                            \
    _Pragma("unroll") for (int rt = 0; rt < 4; ++rt)           \
    _Pragma("unroll") for (int rg = 0; rg < 4; ++rg) {         \
        const int rl = wr * 64 + rt * 16 + quad * 4 + rg;      \
        float e0 = __expf((ACC)[rt][0][rg] * SCALE);           \
        float e1 = __expf((ACC)[rt][1][rg] * SCALE);           \
        bool s0 = dgj && (rl == wc * 32 + l16);                \
        bool s1 = dgj && (rl == wc * 32 + 16 + l16);           \
        colp0 += s0 ? 0.f : e0 * wrow[rt][rg];                 \
        colp1 += s1 ? 0.f : e1 * wrow[rt][rg]; }               \
    colp0 += __shfl_xor(colp0, 16); colp0 += __shfl_xor(colp0, 32); \
    colp1 += __shfl_xor(colp1, 16); colp1 += __shfl_xor(colp1, 32); \
    if (quad == 0) {                                           \
        scs[(JBV) * 128 + wc * 32 + l16][wr]      = colp0;     \
        scs[(JBV) * 128 + wc * 32 + 16 + l16][wr] = colp1; } } while (0)

// ---------------------------------------------------------------------------
// Kernel 1: P = x @ W^T + b (fp32), split to P_hi/P_lo bf16 in d_out.
// ---------------------------------------------------------------------------
__global__ __launch_bounds__(256, 4) void proj_kernel(
    const float* __restrict__ xt, const float* __restrict__ xf,
    const float* __restrict__ W,  const float* __restrict__ bias,
    unsigned short* __restrict__ Ph, unsigned short* __restrict__ Pl)
{
    __shared__ float Alds[64 * 36];
    __shared__ float Blds[128 * 36];
    __shared__ float bs[128];
    const int ns = blockIdx.y;
    const int l0 = blockIdx.x * 64;
    const int src = ns >> 3, n = ns & 7;
    const float* x = (src ? xf : xt) + (size_t)n * LL * DD;
    const int tid = threadIdx.x;
    const int ty = tid >> 4, tx = tid & 15;

    if (tid < 128) bs[tid] = bias[tid];
    __syncthreads();

    float acc[4][8];
#pragma unroll
    for (int i = 0; i < 4; ++i)
#pragma unroll
        for (int j = 0; j < 8; ++j) acc[i][j] = bs[tx + 16 * j];

    for (int kc = 0; kc < 4; ++kc) {
        __syncthreads();
#pragma unroll
        for (int t = 0; t < 2; ++t) {
            int idx = tid + t * 256;
            int r = idx >> 3, k4 = (idx & 7) << 2;
            *(float4*)&Alds[r * 36 + k4] =
                *(const float4*)&x[(size_t)(l0 + r) * DD + kc * 32 + k4];
        }
#pragma unroll
        for (int t = 0; t < 4; ++t) {
            int idx = tid + t * 256;
            int r = idx >> 3, k4 = (idx & 7) << 2;
            *(float4*)&Blds[r * 36 + k4] =
                *(const float4*)&W[(size_t)r * DD + kc * 32 + k4];
        }
        __syncthreads();
#pragma unroll
        for (int k4 = 0; k4 < 32; k4 += 4) {
            float4 a4[4], b4[8];
#pragma unroll
            for (int i = 0; i < 4; ++i) a4[i] = *(const float4*)&Alds[(ty + 16 * i) * 36 + k4];
#pragma unroll
            for (int j = 0; j < 8; ++j) b4[j] = *(const float4*)&Blds[(tx + 16 * j) * 36 + k4];
#pragma unroll
            for (int i = 0; i < 4; ++i)
#pragma unroll
                for (int j = 0; j < 8; ++j) {
                    acc[i][j] = fmaf(a4[i].x, b4[j].x, acc[i][j]);
                    acc[i][j] = fmaf(a4[i].y, b4[j].y, acc[i][j]);
                    acc[i][j] = fmaf(a4[i].z, b4[j].z, acc[i][j]);
                    acc[i][j] = fmaf(a4[i].w, b4[j].w, acc[i][j]);
                }
        }
    }
#pragma unroll
    for (int i = 0; i < 4; ++i) {
        const size_t rowo = (size_t)ns * SLAB + (size_t)(l0 + ty + 16 * i) * DD;
#pragma unroll
        for (int j = 0; j < 8; ++j) {
            float p = acc[i][j];
            unsigned int hb = f2bf(p);
            float hf = __uint_as_float(hb << 16);
            unsigned int lb = f2bf(p - hf);
            Ph[rowo + tx + 16 * j] = (unsigned short)hb;
            Pl[rowo + tx + 16 * j] = (unsigned short)lb;
        }
    }
}

// ---------------------------------------------------------------------------
// Kernel 2 (fused strip): unchanged from R7 (106.9 us, MfmaUtil 42%).
// ---------------------------------------------------------------------------
__global__ __launch_bounds__(512, 2) void score_kernel(
    const unsigned short* __restrict__ Ph, const unsigned short* __restrict__ Pl,
    float* __restrict__ Spart)
{
    __shared__ unsigned short pan[2][4][4096];   // 64 KB B double-buffer
    __shared__ unsigned short Alpan[4][4096];    // 32 KB A-lo panels (static)
    __shared__ float scs[2048][2];               // 16 KB col partials
    __shared__ float zl[128][4];                 // 2 KB Z cross-wave
    int ib, ns;  strip_decode(blockIdx.x, blockIdx.y, ib, ns);
    const int tid = threadIdx.x;
    const int lane = tid & 63, quad = lane >> 4, l16 = lane & 15, wave = tid >> 6;
    const int wr = wave >> 2, wc = wave & 3;

    const unsigned short* sAh = Ph + (size_t)ns * SLAB + (size_t)ib * 128 * DD;
    const unsigned short* sAl = Pl + (size_t)ns * SLAB + (size_t)ib * 128 * DD;
    const unsigned short* sBh = Ph + (size_t)ns * SLAB;
    const unsigned short* sBl = Pl + (size_t)ns * SLAB;

    // ---- prologue: A-lo panels, A-hi regs, first half of jb0 ----
    stage512(sAl,      Alpan[0], tid);
    stage512(sAl + 32, Alpan[1], tid);
    stage512(sAl + 64, Alpan[2], tid);
    stage512(sAl + 96, Alpan[3], tid);
    STAGE_HALF(pan[0], sBh, sBl, 0);
    short8v ah[4][4];
#pragma unroll
    for (int kc = 0; kc < 4; ++kc)
#pragma unroll
        for (int rt = 0; rt < 4; ++rt)
            ah[kc][rt] = *(const short8v*)
                &sAh[(size_t)(wr * 64 + rt * 16 + l16) * DD + kc * 32 + quad * 8];
    __syncthreads();

    float4v accA[4][2], accB[4][2];
    float z[4][4];
#pragma unroll
    for (int rt = 0; rt < 4; ++rt)
#pragma unroll
        for (int rg = 0; rg < 4; ++rg) z[rt][rg] = 0.f;

    // ================= sweep 1: Z row sums =================
#pragma unroll 1
    for (int jp = 0; jp < 8; ++jp) {
        const unsigned short* b0h = sBh + (size_t)(2 * jp) * 128 * DD;
        const unsigned short* b0l = sBl + (size_t)(2 * jp) * 128 * DD;
        const unsigned short* b1h = b0h + 128 * DD;
        const unsigned short* b1l = b0l + 128 * DD;
        const unsigned short* b2h = b1h + 128 * DD;
        const unsigned short* b2l = b1l + 128 * DD;

        ZEROACC(accA);                         // phase A0: jb even, kc0-1
        STAGE_HALF(pan[1], b0h, b0l, 2);
        KC2(accA, pan[0], 0, 0);
        KC2(accA, pan[0], 1, 1);
        if (jp) EPI1(accB);                    // epilogue of jb 2jp-1
        __syncthreads();

        STAGE_HALF(pan[0], b1h, b1l, 0);       // phase A1: jb even, kc2-3
        KC2(accA, pan[1], 0, 2);
        KC2(accA, pan[1], 1, 3);
        __syncthreads();

        ZEROACC(accB);                         // phase B0: jb odd, kc0-1
        STAGE_HALF(pan[1], b1h, b1l, 2);
        KC2(accB, pan[0], 0, 0);
        KC2(accB, pan[0], 1, 1);
        EPI1(accA);                            // epilogue of jb 2jp
        __syncthreads();

        if (jp < 7) STAGE_HALF(pan[0], b2h, b2l, 0);   // phase B1: kc2-3
        KC2(accB, pan[1], 0, 2);
        KC2(accB, pan[1], 1, 3);
        __syncthreads();
    }
    EPI1(accB);                                // jb 15

    // ---- Z reduce -> per-thread iZ row weights ----
#pragma unroll
    for (int rt = 0; rt < 4; ++rt)
#pragma unroll
        for (int rg = 0; rg < 4; ++rg) {
            float s = z[rt][rg];
            s += __shfl_xor(s, 1);
            s += __shfl_xor(s, 2);
            s += __shfl_xor(s, 4);
            s += __shfl_xor(s, 8);
            if (l16 == 0) zl[wr * 64 + rt * 16 + quad * 4 + rg][wc] = s;
        }
    STAGE_HALF(pan[0], sBh, sBl, 0);           // prefetch sweep-2 jb0
    __syncthreads();
    float wrow[4][4];
#pragma unroll
    for (int rt = 0; rt < 4; ++rt)
#pragma unroll
        for (int rg = 0; rg < 4; ++rg) {
            const int row = wr * 64 + rt * 16 + quad * 4 + rg;
            wrow[rt][rg] = 1.0f / (zl[row][0] + zl[row][1] + zl[row][2] + zl[row][3]);
        }

    // ================= sweep 2: weighted col partials =================
#pragma unroll 1
    for (int jp = 0; jp < 8; ++jp) {
        const unsigned short* b0h = sBh + (size_t)(2 * jp) * 128 * DD;
        const unsigned short* b0l = sBl + (size_t)(2 * jp) * 128 * DD;
        const unsigned short* b1h = b0h + 128 * DD;
        const unsigned short* b1l = b0l + 128 * DD;
        const unsigned short* b2h = b1h + 128 * DD;
        const unsigned short* b2l = b1l + 128 * DD;

        ZEROACC(accA);
        STAGE_HALF(pan[1], b0h, b0l, 2);
        KC2(accA, pan[0], 0, 0);
        KC2(accA, pan[0], 1, 1);
        if (jp) EPI2(accB, 2 * jp - 1);
        __syncthreads();

        STAGE_HALF(pan[0], b1h, b1l, 0);
        KC2(accA, pan[1], 0, 2);
        KC2(accA, pan[1], 1, 3);
        __syncthreads();

        ZEROACC(accB);
        STAGE_HALF(pan[1], b1h, b1l, 2);
        KC2(accB, pan[0], 0, 0);
        KC2(accB, pan[0], 1, 1);
        EPI2(accA, 2 * jp);
        __syncthreads();

        if (jp < 7) STAGE_HALF(pan[0], b2h, b2l, 0);
        KC2(accB, pan[1], 0, 2);
        KC2(accB, pan[1], 1, 3);
        __syncthreads();
    }
    EPI2(accB, 15);

    __syncthreads();
#pragma unroll
    for (int g = 0; g < 4; ++g) {
        const int m = tid + g * 512;
        Spart[((size_t)ns * LL + m) * 16 + ib] = scs[m][0] + scs[m][1];
    }
}

// ---------------------------------------------------------------------------
// Kernel 3: exact bottom-k mask via rank counting, PARALLELIZED.
// R7 lesson: old grid (16,2)x1024 put 512 rank-waves on 32 CUs (4/SIMD
// serial, ~48 us, 224 CUs idle). New: grid (16,4)x512 = 64 blocks, ONE row
// per thread, 1 wave/SIMD -> per-wave-latency bound (~8-12 us).
// Each block redundantly rebuilds s[2048] in LDS with the IDENTICAL fp64
// summation order (bitwise-same s); rank count is order-independent.
// j-loop reads double2 (ds_read_b128): 2 compares per LDS read.
// ---------------------------------------------------------------------------
__global__ __launch_bounds__(512) void mask_kernel(
    const float* __restrict__ Spart, unsigned char* __restrict__ maskbuf)
{
    __shared__ double s[LL];
    const int ns = blockIdx.x;
    const int q4 = blockIdx.y;             // 0..3: which 512-row slice we rank
    const int tid = threadIdx.x;
#pragma unroll
    for (int g = 0; g < 4; ++g) {
        int m = tid + g * 512;
        const float* sp = Spart + ((size_t)ns * LL + m) * 16;
        double a = 0.0;
#pragma unroll
        for (int t = 0; t < 16; ++t) a += (double)sp[t];
        s[m] = a;
    }
    __syncthreads();
    const int i = q4 * 512 + tid;
    const double si = s[i];
    const double2* sv = (const double2*)s;
    int cnt = 0;
#pragma unroll 4
    for (int j = 0; j < LL / 2; ++j) {
        double2 p = sv[j];
        cnt += (p.x < si) ? 1 : 0;
        cnt += (p.y < si) ? 1 : 0;
    }
    maskbuf[ns * LL + i] = (cnt < 1024) ? 1 : 0;
}

// ---------------------------------------------------------------------------
// Kernel 4: blend, all fp32.
// ---------------------------------------------------------------------------
__global__ __launch_bounds__(256) void blend_kernel(
    const float* __restrict__ xt, const float* __restrict__ xf,
    const unsigned char* __restrict__ maskbuf, float* __restrict__ out)
{
    const int idx4 = blockIdx.x * 256 + threadIdx.x;
    const size_t q = (size_t)idx4 * 4;
    const int row = (int)(q >> 7);
    const float4 a = *(const float4*)(xt + q);
    const float4 b = *(const float4*)(xf + q);
    const int mt = maskbuf[row] & 1;
    const int mf = maskbuf[16384 + row] & 1;
    const bool ct = mt && !mf;
    const bool cf = mf && !mt;
    float4 av;
    av.x = 0.5f * (a.x + b.x);  av.y = 0.5f * (a.y + b.y);
    av.z = 0.5f * (a.z + b.z);  av.w = 0.5f * (a.w + b.w);
    float4 o0 = ct ? av : a;
    float4 o1 = cf ? av : b;
    *(float4*)(out + q)                   = o0;
    *(float4*)(out + (size_t)2097152 + q) = o1;
}

// ---------------------------------------------------------------------------
extern "C" void kernel_launch(void* const* d_in, const int* in_sizes, int n_in,
                              void* d_out, int out_size, void* d_ws, size_t ws_size,
                              hipStream_t stream)
{
    const float* xt = (const float*)d_in[0];
    const float* xf = (const float*)d_in[1];
    const float* W  = (const float*)d_in[2];
    const float* b  = (const float*)d_in[3];
    float* out = (float*)d_out;

    // d_out (16.8 MB) holds P split: Ph bf16 [0,8.39MB), Pl bf16 [8.39,16.8MB).
    unsigned short* Ph = (unsigned short*)d_out;
    unsigned short* Pl = Ph + (size_t)NS * SLAB;

    float* Spart = (float*)d_ws;                       // 524288 f
    unsigned char* maskbuf = (unsigned char*)(Spart + (size_t)16 * LL * 16);
    // total ws ~2.2 MB

    proj_kernel<<<dim3(32, NS), 256, 0, stream>>>(xt, xf, W, b, Ph, Pl);
    score_kernel<<<dim3(16, 16), 512, 0, stream>>>(Ph, Pl, Spart);
    mask_kernel<<<dim3(NS, 4), 512, 0, stream>>>(Spart, maskbuf);
    blend_kernel<<<2048, 256, 0, stream>>>(xt, xf, maskbuf, out);
}